// Round 1
// baseline (208.810 us; speedup 1.0000x reference)
//
#include <hip/hip_runtime.h>
#include <hip/hip_bf16.h>
#include <stdint.h>

// Problem constants (B=16384, F=2048, K=64), fp32 inputs/outputs.
#define F_DIM 2048
#define K_DIM 64
#define NCHUNK (F_DIM / 32)   // 64 K-steps of 32

typedef float  floatx4 __attribute__((ext_vector_type(4)));
typedef short  short8  __attribute__((ext_vector_type(8)));

__device__ __forceinline__ short f32_to_bf16_rne(float f) {
    unsigned int u = __builtin_bit_cast(unsigned int, f);
    u += 0x7fffu + ((u >> 16) & 1u);            // round-to-nearest-even
    return (short)(u >> 16);
}

// Prep: (a) pack v (2048x64 fp32) into bf16 MFMA B-fragment layout:
//   frag id = c*4 + t (c = f-chunk of 32, t = n-tile of 16), lane l holds
//   B[k = c*32 + (l>>4)*8 + j][n = t*16 + (l&15)], j=0..7 contiguous.
// (b) s[f] = sum_k v[f][k]^2 in fp32 (exact second term).
__global__ __launch_bounds__(256) void fm_prep(const float* __restrict__ v,
                                               short* __restrict__ vp,
                                               float* __restrict__ s) {
    const int bid = blockIdx.x;
    const int tid = threadIdx.x;
    if (bid < 64) {
        const int gid    = bid * 256 + tid;   // 0..16383 fragment-threads
        const int fragid = gid >> 6;          // c*4 + t
        const int l      = gid & 63;
        const int c      = fragid >> 2;
        const int t      = fragid & 3;
        const int fbase  = c * 32 + (l >> 4) * 8;
        const int n      = t * 16 + (l & 15);
        short8 frag;
#pragma unroll
        for (int j = 0; j < 8; ++j)
            frag[j] = f32_to_bf16_rne(v[(size_t)(fbase + j) * K_DIM + n]);
        *reinterpret_cast<short8*>(vp + (size_t)gid * 8) = frag;
    } else {
        const int f = (bid - 64) * 256 + tid; // 0..2047
        const float4* vr = reinterpret_cast<const float4*>(v + (size_t)f * K_DIM);
        float acc = 0.f;
#pragma unroll
        for (int i = 0; i < 16; ++i) {
            float4 q = vr[i];
            acc += q.x * q.x + q.y * q.y + q.z * q.z + q.w * q.w;
        }
        s[f] = acc;
    }
}

// Main: 1 wave (64 threads) per 16-row tile, full-F sweep, K=64 => 4 N-tiles.
// No LDS in the hot loop; A-chunk (and s-chunk) prefetched one iter ahead.
__global__ __launch_bounds__(64) void fm_main(const float* __restrict__ x,
                                              const short* __restrict__ vp,
                                              const float* __restrict__ s,
                                              float* __restrict__ out) {
    const int l = threadIdx.x;
    const int r = l & 15;      // row within tile (A), col within n-tile (B/D)
    const int g = l >> 4;      // k-group / D row-group
    const int row_base = blockIdx.x * 16;

    const float* xp = x + (size_t)(row_base + r) * F_DIM + g * 8;
    const float* sp = s + g * 8;
    const short8* bp = reinterpret_cast<const short8*>(vp) + l;

    floatx4 acc0 = {0.f, 0.f, 0.f, 0.f};
    floatx4 acc1 = acc0, acc2 = acc0, acc3 = acc0;
    float x2s = 0.f;

    float4 aLo = *reinterpret_cast<const float4*>(xp);
    float4 aHi = *reinterpret_cast<const float4*>(xp + 4);
    float4 sLo = *reinterpret_cast<const float4*>(sp);
    float4 sHi = *reinterpret_cast<const float4*>(sp + 4);

    for (int c = 0; c < NCHUNK; ++c) {
        // B fragments for this K-chunk (L2-resident, coalesced dwordx4)
        short8 b0 = bp[0];
        short8 b1 = bp[64];
        short8 b2 = bp[128];
        short8 b3 = bp[192];
        bp += 256;

        // Prefetch next A/s chunk (keeps >=2 HBM dwordx4 in flight per wave)
        float4 naLo = {0.f,0.f,0.f,0.f}, naHi = naLo, nsLo = naLo, nsHi = naLo;
        if (c + 1 < NCHUNK) {
            const float* nx = xp + (c + 1) * 32;
            const float* ns = sp + (c + 1) * 32;
            naLo = *reinterpret_cast<const float4*>(nx);
            naHi = *reinterpret_cast<const float4*>(nx + 4);
            nsLo = *reinterpret_cast<const float4*>(ns);
            nsHi = *reinterpret_cast<const float4*>(ns + 4);
        }

        // Convert A to bf16 fragment (k = g*8 + j, j contiguous)
        short8 a;
        a[0] = f32_to_bf16_rne(aLo.x);
        a[1] = f32_to_bf16_rne(aLo.y);
        a[2] = f32_to_bf16_rne(aLo.z);
        a[3] = f32_to_bf16_rne(aLo.w);
        a[4] = f32_to_bf16_rne(aHi.x);
        a[5] = f32_to_bf16_rne(aHi.y);
        a[6] = f32_to_bf16_rne(aHi.z);
        a[7] = f32_to_bf16_rne(aHi.w);

        // Exact fp32 second term: sum_f x_f^2 * s_f (partial per lane)
        x2s = fmaf(aLo.x * aLo.x, sLo.x, x2s);
        x2s = fmaf(aLo.y * aLo.y, sLo.y, x2s);
        x2s = fmaf(aLo.z * aLo.z, sLo.z, x2s);
        x2s = fmaf(aLo.w * aLo.w, sLo.w, x2s);
        x2s = fmaf(aHi.x * aHi.x, sHi.x, x2s);
        x2s = fmaf(aHi.y * aHi.y, sHi.y, x2s);
        x2s = fmaf(aHi.z * aHi.z, sHi.z, x2s);
        x2s = fmaf(aHi.w * aHi.w, sHi.w, x2s);

        acc0 = __builtin_amdgcn_mfma_f32_16x16x32_bf16(a, b0, acc0, 0, 0, 0);
        acc1 = __builtin_amdgcn_mfma_f32_16x16x32_bf16(a, b1, acc1, 0, 0, 0);
        acc2 = __builtin_amdgcn_mfma_f32_16x16x32_bf16(a, b2, acc2, 0, 0, 0);
        acc3 = __builtin_amdgcn_mfma_f32_16x16x32_bf16(a, b3, acc3, 0, 0, 0);

        aLo = naLo; aHi = naHi; sLo = nsLo; sHi = nsHi;
    }

    // Epilogue. D layout: n = t*16 + (l&15), m = (l>>4)*4 + reg.
    // Square accs (this lane's 4 n's), reduce over low-4 lane bits => sum over all 64 n.
    float sq0 = acc0[0]*acc0[0] + acc1[0]*acc1[0] + acc2[0]*acc2[0] + acc3[0]*acc3[0];
    float sq1 = acc0[1]*acc0[1] + acc1[1]*acc1[1] + acc2[1]*acc2[1] + acc3[1]*acc3[1];
    float sq2 = acc0[2]*acc0[2] + acc1[2]*acc1[2] + acc2[2]*acc2[2] + acc3[2]*acc3[2];
    float sq3 = acc0[3]*acc0[3] + acc1[3]*acc1[3] + acc2[3]*acc2[3] + acc3[3]*acc3[3];
#pragma unroll
    for (int off = 1; off < 16; off <<= 1) {
        sq0 += __shfl_xor(sq0, off, 64);
        sq1 += __shfl_xor(sq1, off, 64);
        sq2 += __shfl_xor(sq2, off, 64);
        sq3 += __shfl_xor(sq3, off, 64);
    }
    // x2s partials live per (row=l&15, group=l>>4): reduce over high-2 bits.
    x2s += __shfl_xor(x2s, 16, 64);
    x2s += __shfl_xor(x2s, 32, 64);

    __shared__ float lds_sq[16];
    if (r == 0) {
        lds_sq[g * 4 + 0] = sq0;
        lds_sq[g * 4 + 1] = sq1;
        lds_sq[g * 4 + 2] = sq2;
        lds_sq[g * 4 + 3] = sq3;
    }
    __syncthreads();
    if (l < 16) {
        // lane l holds full x2s for row l (since l&15 == l)
        out[row_base + l] = 0.5f * (lds_sq[l] - x2s);
    }
}

extern "C" void kernel_launch(void* const* d_in, const int* in_sizes, int n_in,
                              void* d_out, int out_size, void* d_ws, size_t ws_size,
                              hipStream_t stream) {
    const float* x = (const float*)d_in[0];   // (16384, 2048) fp32
    const float* v = (const float*)d_in[1];   // (2048, 64) fp32
    float* out = (float*)d_out;               // (16384,) fp32

    short* vp = (short*)d_ws;                               // 262144 B packed bf16 B-frags
    float* s  = (float*)((char*)d_ws + (size_t)16384 * 16); // 8192 B: s[f]

    fm_prep<<<72, 256, 0, stream>>>(v, vp, s);
    fm_main<<<16384 / 16, 64, 0, stream>>>(x, vp, s, out);
}

// Round 2
// 202.158 us; speedup vs baseline: 1.0329x; 1.0329x over previous
//
#include <hip/hip_runtime.h>
#include <hip/hip_bf16.h>
#include <stdint.h>

// Problem constants (B=16384, F=2048, K=64), fp32 inputs/outputs.
#define F_DIM 2048
#define K_DIM 64

typedef float  floatx4 __attribute__((ext_vector_type(4)));
typedef short  short8  __attribute__((ext_vector_type(8)));

__device__ __forceinline__ short f32_to_bf16_rne(float f) {
    unsigned int u = __builtin_bit_cast(unsigned int, f);
    u += 0x7fffu + ((u >> 16) & 1u);            // round-to-nearest-even
    return (short)(u >> 16);
}

// Prep: (a) pack v (2048x64 fp32) into bf16 MFMA B-fragment layout:
//   frag id = c*4 + t (c = f-chunk of 32, t = n-tile of 16), lane l holds
//   B[k = c*32 + (l>>4)*8 + j][n = t*16 + (l&15)], j=0..7 contiguous.
//   short8 index = c*256 + t*64 + l.
// (b) s[f] = sum_k v[f][k]^2 in fp32 (exact second term).
__global__ __launch_bounds__(256) void fm_prep(const float* __restrict__ v,
                                               short* __restrict__ vp,
                                               float* __restrict__ s) {
    const int bid = blockIdx.x;
    const int tid = threadIdx.x;
    if (bid < 64) {
        const int gid    = bid * 256 + tid;   // 0..16383 fragment-threads
        const int fragid = gid >> 6;          // c*4 + t
        const int l      = gid & 63;
        const int c      = fragid >> 2;
        const int t      = fragid & 3;
        const int fbase  = c * 32 + (l >> 4) * 8;
        const int n      = t * 16 + (l & 15);
        short8 frag;
#pragma unroll
        for (int j = 0; j < 8; ++j)
            frag[j] = f32_to_bf16_rne(v[(size_t)(fbase + j) * K_DIM + n]);
        *reinterpret_cast<short8*>(vp + (size_t)gid * 8) = frag;
    } else {
        const int f = (bid - 64) * 256 + tid; // 0..2047
        const float4* vr = reinterpret_cast<const float4*>(v + (size_t)f * K_DIM);
        float acc = 0.f;
#pragma unroll
        for (int i = 0; i < 16; ++i) {
            float4 q = vr[i];
            acc += q.x * q.x + q.y * q.y + q.z * q.z + q.w * q.w;
        }
        s[f] = acc;
    }
}

// Main: block = 256 threads = 4 waves, one 16-row tile per block.
// Wave w computes partial xv over F-quarter [w*512, (w+1)*512); partials are
// reduced across waves in LDS before squaring. 4096 waves total = 4/SIMD.
__global__ __launch_bounds__(256, 4) void fm_main(const float* __restrict__ x,
                                                  const short* __restrict__ vp,
                                                  const float* __restrict__ s,
                                                  float* __restrict__ out) {
    const int t = threadIdx.x;
    const int w = t >> 6;      // wave id (F-quarter)
    const int l = t & 63;
    const int r = l & 15;      // row within tile (A), col within n-tile (B/D)
    const int g = l >> 4;      // k-group / D row-group
    const int row_base = blockIdx.x * 16;
    const int f0 = w * 512;    // this wave's F range start

    const float*  xp = x + (size_t)(row_base + r) * F_DIM + f0 + g * 8;
    const float*  sp = s + f0 + g * 8;
    const short8* bp = reinterpret_cast<const short8*>(vp) + (size_t)(w * 16) * 256 + l;

    floatx4 acc0 = {0.f, 0.f, 0.f, 0.f};
    floatx4 acc1 = acc0, acc2 = acc0, acc3 = acc0;
    float x2s = 0.f;

    // Iter 0's A chunk (two 32-float K-chunks = 64 floats of this row's F range)
    float4 a0 = *(const float4*)(xp);
    float4 a1 = *(const float4*)(xp + 4);
    float4 a2 = *(const float4*)(xp + 32);
    float4 a3 = *(const float4*)(xp + 36);

    for (int it = 0; it < 8; ++it) {
        // B fragments for the two K-chunks of this iter (L2-resident)
        short8 b00 = bp[0],   b01 = bp[64],  b02 = bp[128], b03 = bp[192];
        short8 b10 = bp[256], b11 = bp[320], b12 = bp[384], b13 = bp[448];
        bp += 512;

        // s values for this iter (8 KB table, L1/L2-hot)
        const float* scur = sp + it * 64;
        float4 s0 = *(const float4*)(scur);
        float4 s1 = *(const float4*)(scur + 4);
        float4 s2 = *(const float4*)(scur + 32);
        float4 s3 = *(const float4*)(scur + 36);

        // Prefetch next iter's A chunk (keeps 4 KB/wave HBM traffic in flight)
        float4 na0 = {0.f,0.f,0.f,0.f}, na1 = na0, na2 = na0, na3 = na0;
        if (it + 1 < 8) {
            const float* nx = xp + (it + 1) * 64;
            na0 = *(const float4*)(nx);
            na1 = *(const float4*)(nx + 4);
            na2 = *(const float4*)(nx + 32);
            na3 = *(const float4*)(nx + 36);
        }

        // ---- K-chunk 0 ----
        short8 af;
        af[0] = f32_to_bf16_rne(a0.x); af[1] = f32_to_bf16_rne(a0.y);
        af[2] = f32_to_bf16_rne(a0.z); af[3] = f32_to_bf16_rne(a0.w);
        af[4] = f32_to_bf16_rne(a1.x); af[5] = f32_to_bf16_rne(a1.y);
        af[6] = f32_to_bf16_rne(a1.z); af[7] = f32_to_bf16_rne(a1.w);

        x2s = fmaf(a0.x * a0.x, s0.x, x2s);
        x2s = fmaf(a0.y * a0.y, s0.y, x2s);
        x2s = fmaf(a0.z * a0.z, s0.z, x2s);
        x2s = fmaf(a0.w * a0.w, s0.w, x2s);
        x2s = fmaf(a1.x * a1.x, s1.x, x2s);
        x2s = fmaf(a1.y * a1.y, s1.y, x2s);
        x2s = fmaf(a1.z * a1.z, s1.z, x2s);
        x2s = fmaf(a1.w * a1.w, s1.w, x2s);

        acc0 = __builtin_amdgcn_mfma_f32_16x16x32_bf16(af, b00, acc0, 0, 0, 0);
        acc1 = __builtin_amdgcn_mfma_f32_16x16x32_bf16(af, b01, acc1, 0, 0, 0);
        acc2 = __builtin_amdgcn_mfma_f32_16x16x32_bf16(af, b02, acc2, 0, 0, 0);
        acc3 = __builtin_amdgcn_mfma_f32_16x16x32_bf16(af, b03, acc3, 0, 0, 0);

        // ---- K-chunk 1 ----
        af[0] = f32_to_bf16_rne(a2.x); af[1] = f32_to_bf16_rne(a2.y);
        af[2] = f32_to_bf16_rne(a2.z); af[3] = f32_to_bf16_rne(a2.w);
        af[4] = f32_to_bf16_rne(a3.x); af[5] = f32_to_bf16_rne(a3.y);
        af[6] = f32_to_bf16_rne(a3.z); af[7] = f32_to_bf16_rne(a3.w);

        x2s = fmaf(a2.x * a2.x, s2.x, x2s);
        x2s = fmaf(a2.y * a2.y, s2.y, x2s);
        x2s = fmaf(a2.z * a2.z, s2.z, x2s);
        x2s = fmaf(a2.w * a2.w, s2.w, x2s);
        x2s = fmaf(a3.x * a3.x, s3.x, x2s);
        x2s = fmaf(a3.y * a3.y, s3.y, x2s);
        x2s = fmaf(a3.z * a3.z, s3.z, x2s);
        x2s = fmaf(a3.w * a3.w, s3.w, x2s);

        acc0 = __builtin_amdgcn_mfma_f32_16x16x32_bf16(af, b10, acc0, 0, 0, 0);
        acc1 = __builtin_amdgcn_mfma_f32_16x16x32_bf16(af, b11, acc1, 0, 0, 0);
        acc2 = __builtin_amdgcn_mfma_f32_16x16x32_bf16(af, b12, acc2, 0, 0, 0);
        acc3 = __builtin_amdgcn_mfma_f32_16x16x32_bf16(af, b13, acc3, 0, 0, 0);

        a0 = na0; a1 = na1; a2 = na2; a3 = na3;
    }

    // ---- Cross-wave reduction of partial xv, then square-reduce ----
    // D layout: n = t*16 + (l&15), m = g*4 + reg. red[w][l][t*4+reg], pad 17.
    __shared__ float red[4][64][17];   // 17.4 KB
    __shared__ float x2r[4][16];
    __shared__ float lds_sq[16];

#pragma unroll
    for (int j = 0; j < 4; ++j) {
        red[w][l][j]      = acc0[j];
        red[w][l][4 + j]  = acc1[j];
        red[w][l][8 + j]  = acc2[j];
        red[w][l][12 + j] = acc3[j];
    }
    // x2s partials: per (row=r, group=g); reduce over g (high 2 lane bits)
    x2s += __shfl_xor(x2s, 16, 64);
    x2s += __shfl_xor(x2s, 32, 64);
    if (g == 0) x2r[w][r] = x2s;
    __syncthreads();

    if (w == 0) {
        float vsum[16];
#pragma unroll
        for (int j = 0; j < 16; ++j)
            vsum[j] = red[0][l][j] + red[1][l][j] + red[2][l][j] + red[3][l][j];
        // sq_reg = sum over n-tiles of xv[m=g*4+reg][n]^2 (this lane's 4 n's)
        float sq0 = vsum[0]*vsum[0] + vsum[4]*vsum[4] + vsum[8]*vsum[8]  + vsum[12]*vsum[12];
        float sq1 = vsum[1]*vsum[1] + vsum[5]*vsum[5] + vsum[9]*vsum[9]  + vsum[13]*vsum[13];
        float sq2 = vsum[2]*vsum[2] + vsum[6]*vsum[6] + vsum[10]*vsum[10] + vsum[14]*vsum[14];
        float sq3 = vsum[3]*vsum[3] + vsum[7]*vsum[7] + vsum[11]*vsum[11] + vsum[15]*vsum[15];
#pragma unroll
        for (int off = 1; off < 16; off <<= 1) {
            sq0 += __shfl_xor(sq0, off, 64);
            sq1 += __shfl_xor(sq1, off, 64);
            sq2 += __shfl_xor(sq2, off, 64);
            sq3 += __shfl_xor(sq3, off, 64);
        }
        if (r == 0) {
            lds_sq[g * 4 + 0] = sq0;
            lds_sq[g * 4 + 1] = sq1;
            lds_sq[g * 4 + 2] = sq2;
            lds_sq[g * 4 + 3] = sq3;
        }
    }
    __syncthreads();
    if (t < 16) {
        float x2full = x2r[0][t] + x2r[1][t] + x2r[2][t] + x2r[3][t];
        out[row_base + t] = 0.5f * (lds_sq[t] - x2full);
    }
}

extern "C" void kernel_launch(void* const* d_in, const int* in_sizes, int n_in,
                              void* d_out, int out_size, void* d_ws, size_t ws_size,
                              hipStream_t stream) {
    const float* x = (const float*)d_in[0];   // (16384, 2048) fp32
    const float* v = (const float*)d_in[1];   // (2048, 64) fp32
    float* out = (float*)d_out;               // (16384,) fp32

    short* vp = (short*)d_ws;                               // 262144 B packed bf16 B-frags
    float* s  = (float*)((char*)d_ws + (size_t)16384 * 16); // 8192 B: s[f]

    fm_prep<<<72, 256, 0, stream>>>(v, vp, s);
    fm_main<<<16384 / 16, 256, 0, stream>>>(x, vp, s, out);
}